// Round 3
// baseline (497.922 us; speedup 1.0000x reference)
//
#include <hip/hip_runtime.h>
#include <cstdint>
#include <cstddef>

typedef __bf16 bf16;
typedef __bf16 bf16x8 __attribute__((ext_vector_type(8)));
typedef float  f32x4  __attribute__((ext_vector_type(4)));
typedef float  f32x8  __attribute__((ext_vector_type(8)));

#define MDIM 2048
#define NDIM 4096
#define KDIM 4096
#define FLOATMAX 3.402823466e38f

// ---------------- fp32 -> bf16 conversion, 16B stores ----------------
__global__ void cvt2_f32_to_bf16(const float* __restrict__ x, const float* __restrict__ w,
                                 bf16* __restrict__ xb, bf16* __restrict__ wb,
                                 int xn8, int wn8) {
    const int stride = gridDim.x * blockDim.x;
    int i = blockIdx.x * blockDim.x + threadIdx.x;
    for (int k = i; k < xn8; k += stride) {
        f32x4 lo = reinterpret_cast<const f32x4*>(x)[2 * k];
        f32x4 hi = reinterpret_cast<const f32x4*>(x)[2 * k + 1];
        f32x8 v = {lo[0], lo[1], lo[2], lo[3], hi[0], hi[1], hi[2], hi[3]};
        reinterpret_cast<bf16x8*>(xb)[k] = __builtin_convertvector(v, bf16x8);
    }
    for (int k = i; k < wn8; k += stride) {
        f32x4 lo = reinterpret_cast<const f32x4*>(w)[2 * k];
        f32x4 hi = reinterpret_cast<const f32x4*>(w)[2 * k + 1];
        f32x8 v = {lo[0], lo[1], lo[2], lo[3], hi[0], hi[1], hi[2], hi[3]};
        reinterpret_cast<bf16x8*>(wb)[k] = __builtin_convertvector(v, bf16x8);
    }
}

// async global->LDS, 16B per lane (HW: wave-uniform LDS base + lane*16)
__device__ __forceinline__ void g2lds16(const bf16* g, bf16* l) {
    __builtin_amdgcn_global_load_lds(
        (const __attribute__((address_space(1))) uint32_t*)g,
        (__attribute__((address_space(3))) uint32_t*)l, 16, 0, 0);
}

// ---------------- MAM main kernel (split-K over the 2 SPLITS) ----------------
// Grid (N/128, M/128, 2). Block 256 threads = 4 waves in 2(m) x 2(n); wave tile 64x64
// = 4x4 MFMA 16x16 tiles. Per block: K=2048 as 32 stages of BK=64 (2 ACCBLOCKs).
// LDS double-buffered (64 KB total) -> 2 blocks/CU resident (128 KB), so barriers of
// one block overlap with compute of the other. Split partials combined with
// fp32 HW atomics into pre-zeroed out (2 commutative adds -> deterministic).
__global__ __launch_bounds__(256, 2) void mam_kernel(
    const bf16* __restrict__ A,   // [M,K] bf16 (x)
    const bf16* __restrict__ B,   // [N,K] bf16 (weight row n = col n of w)
    const float* __restrict__ bias,
    float* __restrict__ out)
{
    __shared__ __align__(16) bf16 sA[2][2][128 * 32];  // [parity][accblock-half]
    __shared__ __align__(16) bf16 sB[2][2][128 * 32];

    const int t    = threadIdx.x;
    const int lane = t & 63;
    const int w    = t >> 6;        // 0..3
    const int wm   = (w >> 1) * 64; // 0 or 64
    const int wn   = (w & 1) * 64;  // 0 or 64

    const int m0 = blockIdx.y * 128;
    const int n0 = blockIdx.x * 128;
    const int split = blockIdx.z;               // 0 or 1
    const size_t kbase = (size_t)split * 2048;  // split base along K

    // staging: 256 threads x 2 issues cover 128 rows x 32 bf16 per buffer.
    // issue i: row r = i*64 + (t>>2), slot p = t&3; fetch global chunk p ^ ((r>>1)&3)
    const bf16* gAi[2];
    const bf16* gBi[2];
    int ldsOff[2];
#pragma unroll
    for (int i = 0; i < 2; ++i) {
        const int r = i * 64 + (t >> 2);
        const int p = t & 3;
        const int c = p ^ ((r >> 1) & 3);
        gAi[i] = A + (size_t)(m0 + r) * KDIM + kbase + c * 8;
        gBi[i] = B + (size_t)(n0 + r) * KDIM + kbase + c * 8;
        ldsOff[i] = (i * 256 + t) * 8;  // bf16 elements; 16B per thread per issue
    }

    // fragment addressing: row R, chunk q=lane>>4 lives at slot q ^ ((R>>1)&3)
    const int frow = lane & 15;
    const int q    = lane >> 4;
    int offA[4], offB[4];
#pragma unroll
    for (int i = 0; i < 4; ++i) {
        const int RA = wm + i * 16 + frow;
        offA[i] = RA * 32 + (q ^ ((RA >> 1) & 3)) * 8;
        const int RB = wn + i * 16 + frow;
        offB[i] = RB * 32 + (q ^ ((RB >> 1) & 3)) * 8;
    }

    const f32x4 kZero = {0.f, 0.f, 0.f, 0.f};

    f32x4 mx[4][4], mn[4][4];
#pragma unroll
    for (int i = 0; i < 4; ++i)
#pragma unroll
        for (int j = 0; j < 4; ++j) {
            mx[i][j] = (f32x4)(-FLOATMAX);
            mn[i][j] = (f32x4)(FLOATMAX);
        }

    auto prefetch = [&](int s, int pb) {
        const size_t so = (size_t)s * 64;
#pragma unroll
        for (int i = 0; i < 2; ++i) {
            g2lds16(gAi[i] + so,      &sA[pb][0][ldsOff[i]]);
            g2lds16(gAi[i] + so + 32, &sA[pb][1][ldsOff[i]]);
            g2lds16(gBi[i] + so,      &sB[pb][0][ldsOff[i]]);
            g2lds16(gBi[i] + so + 32, &sB[pb][1][ldsOff[i]]);
        }
    };

    auto compute = [&](int pb) {
        bf16x8 aF0[4], aF1[4], bF0[4], bF1[4];
#pragma unroll
        for (int i = 0; i < 4; ++i) {
            aF0[i] = *(const bf16x8*)&sA[pb][0][offA[i]];
            aF1[i] = *(const bf16x8*)&sA[pb][1][offA[i]];
            bF0[i] = *(const bf16x8*)&sB[pb][0][offB[i]];
            bF1[i] = *(const bf16x8*)&sB[pb][1][offB[i]];
        }
#pragma unroll
        for (int i = 0; i < 4; ++i) {
#pragma unroll
            for (int j = 0; j < 4; ++j) {
                f32x4 s0 = __builtin_amdgcn_mfma_f32_16x16x32_bf16(
                    aF0[i], bF0[j], kZero, 0, 0, 0);
                f32x4 s1 = __builtin_amdgcn_mfma_f32_16x16x32_bf16(
                    aF1[i], bF1[j], kZero, 0, 0, 0);
#pragma unroll
                for (int r = 0; r < 4; ++r) {
                    mx[i][j][r] = fmaxf(fmaxf(mx[i][j][r], s0[r]), s1[r]);  // v_max3_f32
                    mn[i][j][r] = fminf(fminf(mn[i][j][r], s0[r]), s1[r]);  // v_min3_f32
                }
            }
        }
    };

    prefetch(0, 0);

#pragma unroll 1
    for (int it = 0; it < 16; ++it) {
        __syncthreads();
        prefetch(2 * it + 1, 1);
        compute(0);
        __syncthreads();
        if (it < 15) prefetch(2 * it + 2, 0);
        compute(1);
    }

    // epilogue: C/D layout col=lane&15, row=(lane>>4)*4+reg; atomic split-combine
    const int orow = (lane >> 4) * 4;
    const int ocol = lane & 15;
#pragma unroll
    for (int j = 0; j < 4; ++j) {
        const int col = n0 + wn + j * 16 + ocol;
        const float bv = (split == 0) ? bias[col] : 0.0f;
#pragma unroll
        for (int i = 0; i < 4; ++i) {
            const int row = m0 + wm + i * 16 + orow;
#pragma unroll
            for (int r = 0; r < 4; ++r) {
                const float v = mx[i][j][r] + mn[i][j][r] + bv;
                unsafeAtomicAdd(&out[(size_t)(row + r) * NDIM + col], v);
            }
        }
    }
}

extern "C" void kernel_launch(void* const* d_in, const int* in_sizes, int n_in,
                              void* d_out, int out_size, void* d_ws, size_t ws_size,
                              hipStream_t stream) {
    const float* x    = (const float*)d_in[0];  // [M,K]
    const float* wgt  = (const float*)d_in[1];  // [N,K]
    const float* bias = (const float*)d_in[2];  // [N]
    float* out = (float*)d_out;

    bf16* xbf = (bf16*)d_ws;                        // M*K bf16 = 16 MiB
    bf16* wbf = xbf + (size_t)MDIM * KDIM;          // N*K bf16 = 32 MiB

    const int xn8 = (MDIM * KDIM) / 8;
    const int wn8 = (NDIM * KDIM) / 8;
    cvt2_f32_to_bf16<<<dim3(4096), dim3(256), 0, stream>>>(x, wgt, xbf, wbf, xn8, wn8);

    // zero out for the atomic split-combine (graph-capturable async memset)
    hipMemsetAsync(d_out, 0, (size_t)MDIM * NDIM * sizeof(float), stream);

    dim3 grid(NDIM / 128, MDIM / 128, 2);  // (32, 16, 2)
    mam_kernel<<<grid, dim3(256), 0, stream>>>(xbf, wbf, bias, out);
}